// Round 3
// baseline (699.604 us; speedup 1.0000x reference)
//
#include <hip/hip_runtime.h>

#define B_   16
#define L_   1536
#define D_   512
#define DFF_ 2048
#define NM   64
#define HID  256

typedef short short8  __attribute__((ext_vector_type(8)));
typedef short short4v __attribute__((ext_vector_type(4)));
typedef float f32x4   __attribute__((ext_vector_type(4)));

__device__ __forceinline__ float b2f(short s) {
  unsigned int u = ((unsigned int)(unsigned short)s) << 16;
  float f; __builtin_memcpy(&f, &u, 4); return f;
}
__device__ __forceinline__ short f2b(float f) {
  unsigned int u; __builtin_memcpy(&u, &f, 4);
  u += 0x7fffu + ((u >> 16) & 1u);
  return (short)(u >> 16);
}
__device__ __forceinline__ f32x4 zero4() {
  f32x4 v; v[0]=0.f; v[1]=0.f; v[2]=0.f; v[3]=0.f; return v;
}

#define MFMA(a,b,c) __builtin_amdgcn_mfma_f32_16x16x32_bf16((a),(b),(c),0,0,0)
// XOR-swizzled LDS offset (shorts) for 64-short rows: row*64 + (grp^(row&7))*8
#define SWZ(row, grp) (((row) << 6) + ((((grp) ^ ((row) & 7))) << 3))
// async 16B/lane global->LDS (m97: width 16 => global_load_lds_dwordx4)
#define GLDS16(gp, lp) __builtin_amdgcn_global_load_lds( \
    (const __attribute__((address_space(1))) void*)(gp), \
    (__attribute__((address_space(3))) void*)(lp), 16, 0, 0)

// ---------------- guard: zero output (ws too small diagnostic) ----------------
__global__ __launch_bounds__(256) void zero_out(float* __restrict__ o, int n) {
  int i = blockIdx.x * 256 + threadIdx.x;
  if (i < n) o[i] = 0.f;
}

// ---------------- fp32 -> bf16 convert ----------------
__global__ __launch_bounds__(256) void cvt_f32_bf16(const float* __restrict__ s,
                                                    short* __restrict__ d, int n4) {
  int i = blockIdx.x * 256 + threadIdx.x;
  if (i >= n4) return;
  f32x4 v = ((const f32x4*)s)[i];
  short4v o;
  #pragma unroll
  for (int j = 0; j < 4; ++j) o[j] = f2b(v[j]);
  ((short4v*)d)[i] = o;
}

// ---------------- DFT tables ----------------
// tcs[m][l], m<64: cos(2pi m l/L); m in 64..127: -sin(2pi (m-64) l/L)
__global__ __launch_bounds__(256) void build_tcs(short* __restrict__ tcs) {
  int i = blockIdx.x * 256 + threadIdx.x;
  if (i >= 128 * L_) return;
  int m = i / L_, l = i - m * L_;
  int mm = (m < 64) ? m : (m - 64);
  int r = (mm * l) % L_;                      // exact integer angle reduction
  float th = (float)r * (6.283185307179586f / (float)L_);
  float s, c; __sincosf(th, &s, &c);
  tcs[i] = f2b((m < 64) ? c : -s);
}
// basis[l][k]: k<64 -> ((k==0?1:2)/L)*cos(2pi k l/L); k>=64 -> (-2/L)*sin(2pi (k-64) l/L)
__global__ __launch_bounds__(256) void build_basis(short* __restrict__ basis) {
  int i = blockIdx.x * 256 + threadIdx.x;
  if (i >= L_ * 128) return;
  int l = i >> 7, k = i & 127;
  int m = (k < 64) ? k : (k - 64);
  int r = (m * l) % L_;
  float th = (float)r * (6.283185307179586f / (float)L_);
  float s, c; __sincosf(th, &s, &c);
  float v = (k < 64) ? ((m == 0) ? 1.f : 2.f) * (1.f / (float)L_) * c
                     : (-2.f / (float)L_) * s;
  basis[i] = f2b(v);
}

// ---------------- w[d][e][m] f32 -> wt[m][e][d] bf16 (16 modes per grid.z) ----------------
__global__ __launch_bounds__(256) void transpose_w(const float* __restrict__ w,
                                                   short* __restrict__ wt) {
  __shared__ float tile[64][17];
  int dc = blockIdx.x, e = blockIdx.y, t = threadIdx.x;
  int mBase = blockIdx.z * 16;
  {
    int dl = t >> 2, mg = t & 3;
    f32x4 v = *(const f32x4*)(w + ((long)(dc * 64 + dl) * 512 + e) * 64 + mBase + mg * 4);
    tile[dl][mg*4+0] = v[0]; tile[dl][mg*4+1] = v[1];
    tile[dl][mg*4+2] = v[2]; tile[dl][mg*4+3] = v[3];
  }
  __syncthreads();
  if (t < 128) {
    int mr = t >> 3, dg = t & 7;
    short8 o;
    #pragma unroll
    for (int j = 0; j < 8; ++j) o[j] = f2b(tile[dg * 8 + j][mr]);
    *(short8*)(wt + ((long)(mBase + mr) * 512 + e) * 512 + dc * 64 + dg * 8) = o;
  }
}

// ---------------- x[b][l][d] f32 -> xt[b][d][l] bf16 ----------------
__global__ __launch_bounds__(256) void transpose_x(const float* __restrict__ x,
                                                   short* __restrict__ xt) {
  __shared__ float tile[64][65];
  int dc = blockIdx.x, lc = blockIdx.y, b = blockIdx.z, t = threadIdx.x;
  const float* xb = x + (long)b * L_ * D_;
  #pragma unroll
  for (int i = 0; i < 4; ++i) {
    int idx = i * 256 + t; int ll = idx >> 4, dg = idx & 15;
    f32x4 v = *(const f32x4*)(xb + (long)(lc * 64 + ll) * D_ + dc * 64 + dg * 4);
    tile[ll][dg*4+0] = v[0]; tile[ll][dg*4+1] = v[1];
    tile[ll][dg*4+2] = v[2]; tile[ll][dg*4+3] = v[3];
  }
  __syncthreads();
  #pragma unroll
  for (int i = 0; i < 2; ++i) {
    int idx = i * 256 + t; int dl = idx >> 3, lg = idx & 7;
    short8 o;
    #pragma unroll
    for (int j = 0; j < 8; ++j) o[j] = f2b(tile[lg * 8 + j][dl]);
    *(short8*)(xt + ((long)b * D_ + dc * 64 + dl) * L_ + lc * 64 + lg * 8) = o;
  }
}

// ---------------- qt (8192 x 128) bf16 -> q (128 x 8192) bf16 ----------------
__global__ __launch_bounds__(256) void transpose_q(const short* __restrict__ in,
                                                   short* __restrict__ out) {
  __shared__ short tile[64][72];
  int ct = blockIdx.x, rt = blockIdx.y, t = threadIdx.x;
  int r0 = rt * 64, c0 = ct * 64;
  #pragma unroll
  for (int i = 0; i < 2; ++i) {
    int idx = i * 256 + t; int r = idx >> 3, g = idx & 7;
    short8 v = *(const short8*)(in + (long)(r0 + r) * 128 + c0 + g * 8);
    #pragma unroll
    for (int j = 0; j < 8; ++j) tile[r][g * 8 + j] = v[j];
  }
  __syncthreads();
  #pragma unroll
  for (int i = 0; i < 2; ++i) {
    int idx = i * 256 + t; int c = idx >> 3, g = idx & 7;
    short8 o;
    #pragma unroll
    for (int j = 0; j < 8; ++j) o[j] = tile[g * 8 + j][c];
    *(short8*)(out + (long)(c0 + c) * 8192 + r0 + g * 8) = o;
  }
}

// ---------------- 128x128-tile bf16 MFMA GEMM (m97 structure) ----------------
// C = act(A * W^T + bias) + res.  A:(M,K) row-major bf16; W:(N,K) row-major bf16.
// out bf16 row-major (ldC, batch Cz). res: fp32 (RESB=0) or bf16 (RESB=1).
// Staging: global_load_lds width=16, XOR-swizzled LDS (swizzle inverted on src addr).
template<bool RELU, bool HASBIAS, bool HASRES, bool RESB>
__global__ __launch_bounds__(256) void gemm128(
    const short* __restrict__ A, long ldA, long Az,
    const short* __restrict__ W, long ldW, long Wz,
    const float* __restrict__ bias,
    const void* __restrict__ res, long ldres, long resZ,
    short* __restrict__ outB, long ldC, long Cz, int K)
{
  __shared__ short lA[128 * 64];
  __shared__ short lW[128 * 64];
  const int t = threadIdx.x, lane = t & 63, wid = t >> 6;
  const int quad = lane >> 4, l15 = lane & 15;
  const int wm = (wid & 1) * 64, wn = (wid >> 1) * 64;
  const long row0 = (long)blockIdx.x * 128, col0 = (long)blockIdx.y * 128;
  const int z = blockIdx.z;
  const short* Ab = A + (long)z * Az + row0 * ldA;
  const short* Wb = W + (long)z * Wz + col0 * ldW;

  // staging geometry: 16 chunks of 1KB per matrix; chunk c = rows 8c..8c+7.
  // lane's LDS slot (fixed) = chunk + lane*16B = row r=8c+(lane>>3), pos p=lane&7;
  // slot p holds logical k-group g = p ^ (r&7)  -> invert swizzle on the source.
  int srcrow[4]; long srcoff[4];
  #pragma unroll
  for (int i = 0; i < 4; ++i) {
    int c = wid * 4 + i;
    int r = c * 8 + (lane >> 3);
    int g = (lane & 7) ^ (r & 7);
    srcrow[i] = r; srcoff[i] = g * 8;
  }

  f32x4 acc[4][4];
  #pragma unroll
  for (int i = 0; i < 4; ++i)
    #pragma unroll
    for (int j = 0; j < 4; ++j) acc[i][j] = zero4();

  for (int k0 = 0; k0 < K; k0 += 64) {
    __syncthreads();
    #pragma unroll
    for (int i = 0; i < 4; ++i) {
      int c = wid * 4 + i;
      GLDS16(Ab + (long)srcrow[i] * ldA + k0 + srcoff[i], lA + c * 512);
      GLDS16(Wb + (long)srcrow[i] * ldW + k0 + srcoff[i], lW + c * 512);
    }
    __syncthreads();   // compiler drains vmcnt before s_barrier -> LDS ready
    #pragma unroll
    for (int ks = 0; ks < 2; ++ks) {
      int gq = ks * 4 + quad;
      short8 av[4], bv[4];
      #pragma unroll
      for (int mi = 0; mi < 4; ++mi) av[mi] = *(const short8*)&lA[SWZ(wm + mi * 16 + l15, gq)];
      #pragma unroll
      for (int ni = 0; ni < 4; ++ni) bv[ni] = *(const short8*)&lW[SWZ(wn + ni * 16 + l15, gq)];
      #pragma unroll
      for (int mi = 0; mi < 4; ++mi)
        #pragma unroll
        for (int ni = 0; ni < 4; ++ni)
          acc[mi][ni] = MFMA(av[mi], bv[ni], acc[mi][ni]);
    }
  }
  // C/D layout: col=lane&15, row=quad*4+reg (verified m89/m91)
  #pragma unroll
  for (int ni = 0; ni < 4; ++ni) {
    long col = col0 + wn + ni * 16 + l15;
    float bvv = HASBIAS ? bias[col] : 0.f;
    #pragma unroll
    for (int mi = 0; mi < 4; ++mi) {
      #pragma unroll
      for (int r = 0; r < 4; ++r) {
        long row = row0 + wm + mi * 16 + quad * 4 + r;
        float v = acc[mi][ni][r];
        if (HASBIAS) v += bvv;
        if (RELU)    v = fmaxf(v, 0.f);
        if (HASRES) {
          long ro = (long)z * resZ + row * ldres + col;
          v += RESB ? b2f(((const short*)res)[ro]) : ((const float*)res)[ro];
        }
        outB[(long)z * Cz + row * ldC + col] = f2b(v);
      }
    }
  }
}

// ---------------- per-mode complex GEMM ----------------
// qr/qi: [m][b][d] bf16; wr/wi: [m][e][d] bf16; outm: (b,e,128) bf16 [0:64 re | 64:128 im]
__global__ __launch_bounds__(256) void mode_gemm(
    const short* __restrict__ qr, const short* __restrict__ qi,
    const short* __restrict__ wr, const short* __restrict__ wi,
    short* __restrict__ outm)
{
  __shared__ short lqr[16 * 64], lqi[16 * 64], lwr[64 * 64], lwi[64 * 64];
  const int m = blockIdx.x, en = blockIdx.y;
  const int t = threadIdx.x, lane = t & 63, wid = t >> 6;
  const int quad = lane >> 4, l15 = lane & 15;
  const short* qrb = qr + (long)m * (B_ * D_);
  const short* qib = qi + (long)m * (B_ * D_);
  const short* wrb = wr + (long)m * (D_ * D_) + (long)en * 64 * D_;
  const short* wib = wi + (long)m * (D_ * D_) + (long)en * 64 * D_;
  f32x4 accr = zero4(), acci = zero4();
  for (int k0 = 0; k0 < D_; k0 += 64) {
    __syncthreads();
    {
      int idx = t & 127; int r = idx >> 3, cg = idx & 7;
      const short* src = (t < 128 ? qrb : qib) + r * D_ + k0 + cg * 8;
      short* dst = (t < 128) ? lqr : lqi;
      *(short8*)&dst[SWZ(r, cg)] = *(const short8*)src;
    }
    #pragma unroll
    for (int i = 0; i < 4; ++i) {
      int idx = i * 256 + t;
      int which = idx >> 9, idx2 = idx & 511;
      int r = idx2 >> 3, cg = idx2 & 7;
      const short* src = (which ? wib : wrb) + r * D_ + k0 + cg * 8;
      short* dst = which ? lwi : lwr;
      *(short8*)&dst[SWZ(r, cg)] = *(const short8*)src;
    }
    __syncthreads();
    #pragma unroll
    for (int ks = 0; ks < 2; ++ks) {
      int gq = ks * 4 + quad;
      short8 ar = *(const short8*)&lqr[SWZ(l15, gq)];
      short8 ai = *(const short8*)&lqi[SWZ(l15, gq)];
      short8 br = *(const short8*)&lwr[SWZ(wid * 16 + l15, gq)];
      short8 bi = *(const short8*)&lwi[SWZ(wid * 16 + l15, gq)];
      short8 nai;
      #pragma unroll
      for (int j = 0; j < 8; ++j) nai[j] = (short)(ai[j] ^ (short)0x8000);
      accr = MFMA(ar, br, accr);
      accr = MFMA(nai, bi, accr);   // - qi*wi
      acci = MFMA(ar, bi, acci);
      acci = MFMA(ai, br, acci);
    }
  }
  #pragma unroll
  for (int r = 0; r < 4; ++r) {
    int bb = quad * 4 + r;                       // row = b (M=16 exact)
    long e = (long)en * 64 + wid * 16 + l15;     // col = e
    long base = ((long)bb * D_ + e) * 128 + m;
    outm[base]      = f2b(accr[r]);
    outm[base + 64] = f2b(acci[r]);
  }
}

// ---------------- 3-expert gates: softmax(h @ w2^T + b2) ----------------
__global__ __launch_bounds__(256) void gates_kernel(
    const short* __restrict__ h, const float* __restrict__ w2,
    const float* __restrict__ b2, float* __restrict__ g, int rows)
{
  int wid = threadIdx.x >> 6, lane = threadIdx.x & 63;
  int row = blockIdx.x * 4 + wid;
  if (row >= rows) return;
  const short* hr = h + (long)row * HID;
  short4v hh = *(const short4v*)(hr + lane * 4);
  float hv[4];
  #pragma unroll
  for (int j = 0; j < 4; ++j) hv[j] = b2f(hh[j]);
  float lg[3];
  #pragma unroll
  for (int e = 0; e < 3; ++e) {
    const float* wrow = w2 + e * HID + lane * 4;
    float p = hv[0] * wrow[0] + hv[1] * wrow[1] + hv[2] * wrow[2] + hv[3] * wrow[3];
    #pragma unroll
    for (int off = 32; off >= 1; off >>= 1) p += __shfl_xor(p, off);
    lg[e] = p + b2[e];
  }
  float mx = fmaxf(lg[0], fmaxf(lg[1], lg[2]));
  float e0 = __expf(lg[0] - mx), e1 = __expf(lg[1] - mx), e2 = __expf(lg[2] - mx);
  float inv = 1.f / (e0 + e1 + e2);
  float gv = (lane == 0) ? e0 * inv : (lane == 1) ? e1 * inv : e2 * inv;
  if (lane < 3) g[(long)row * 3 + lane] = gv;
}

// ---------------- seasonal combine: out = x - sum_e gate_e * avgpool_{3,5,7}(x) ----------------
template<bool OUTF, bool WRITEB>
__global__ __launch_bounds__(512) void combine_kernel(
    const short* __restrict__ xin, const float* __restrict__ g,
    float* __restrict__ outf, short* __restrict__ outb)
{
  int lc = blockIdx.x, b = blockIdx.y, d = threadIdx.x;
  int l0 = lc * 64;
  const short* xb = xin + (long)b * L_ * D_ + d;
  const float* gb = g + (long)b * L_ * 3;
  float win[7];
  #pragma unroll
  for (int j = 0; j < 6; ++j) {
    int l = l0 - 3 + j;
    win[j] = (l >= 0 && l < L_) ? b2f(xb[(long)l * D_]) : 0.f;
  }
  for (int i = 0; i < 64; ++i) {
    int lcn = l0 + i;
    int lr = lcn + 3;
    win[6] = (lr < L_) ? b2f(xb[(long)lr * D_]) : 0.f;
    float s3 = win[2] + win[3] + win[4];
    float s5 = s3 + win[1] + win[5];
    float s7 = s5 + win[0] + win[6];
    float g0 = gb[lcn * 3 + 0], g1 = gb[lcn * 3 + 1], g2 = gb[lcn * 3 + 2];
    float trend = g0 * s3 * (1.f / 3.f) + g1 * s5 * (1.f / 5.f) + g2 * s7 * (1.f / 7.f);
    float v = win[3] - trend;
    long o = ((long)b * L_ + lcn) * D_ + d;
    if (OUTF)   outf[o] = v;
    if (WRITEB) outb[o] = f2b(v);
    #pragma unroll
    for (int j = 0; j < 6; ++j) win[j] = win[j + 1];
  }
}

extern "C" void kernel_launch(void* const* d_in, const int* in_sizes, int n_in,
                              void* d_out, int out_size, void* d_ws, size_t ws_size,
                              hipStream_t stream) {
  const float* x       = (const float*)d_in[0];
  const float* w_real  = (const float*)d_in[1];
  const float* w_imag  = (const float*)d_in[2];
  const float* conv1_w = (const float*)d_in[3];
  const float* conv2_w = (const float*)d_in[4];
  const float* d1_w1   = (const float*)d_in[5];
  const float* d1_b1   = (const float*)d_in[6];
  const float* d1_w2   = (const float*)d_in[7];
  const float* d1_b2   = (const float*)d_in[8];
  const float* d2_w1   = (const float*)d_in[9];
  const float* d2_b1   = (const float*)d_in[10];
  const float* d2_w2   = (const float*)d_in[11];
  const float* d2_b2   = (const float*)d_in[12];
  float* OUT = (float*)d_out;

  // ---- workspace guard: peak arena = 106,954,752 B (~102 MB); R2's 110MB passed ----
  const size_t REQUIRED = 106954752;
  if (ws_size < REQUIRED) {
    zero_out<<<(out_size + 255) / 256, 256, 0, stream>>>(OUT, out_size);
    return;
  }

  char* ws = (char*)d_ws;
  // Arena with lifetime aliasing (phases: prep -> fwdDFT -> modes -> invDFT ->
  // decomp1 -> FFN -> decomp2):
  short* C1WB  = (short*)(ws + 0);          //  2,097,152   [live: all]
  short* C2WB  = (short*)(ws + 2097152);    //  2,097,152
  short* D1W1B = (short*)(ws + 4194304);    //    262,144
  short* D2W1B = (short*)(ws + 4456448);    //    262,144
  short* TCS   = (short*)(ws + 4718592);    //    393,216
  short* BASIS = (short*)(ws + 5111808);    //    393,216
  float* G     = (float*)(ws + 5505024);    //    294,912  (pad to 6,291,456)
  short* XT    = (short*)(ws + 6291456);    // 25,165,824  [dead after fwdDFT]
  short* QRI   = XT;                        //  2,097,152  [alias; dead after modes]
  short* Y1C   = XT;                        // 25,165,824  [alias; FFN phase]
  short* QT    = (short*)(ws + 31457280);   //  2,097,152  [dead after transpose_q]
  short* ZB    = QT;                        // 25,165,824  [alias; FFN out, ->ends 56,623,104]
  short* OUTM  = (short*)(ws + 33554432);   //  2,097,152  [dead after invDFT]
  short* WTR   = (short*)(ws + 35651584);   // 33,554,432  [dead after modes]
  short* X1B   = WTR;                       // 25,165,824  [alias; dead after combine1]
  short* WTI   = (short*)(ws + 69206016);   // 33,554,432  [dead after modes]
  short* X2B   = WTI;                       // 25,165,824  [alias; live thru FFN]
  short* H     = (short*)(ws + 94371840);   // 12,582,912  -> peak 106,954,752

  // --- weight prep ---
  cvt_f32_bf16<<<(262144 + 255) / 256, 256, 0, stream>>>(conv1_w, C1WB, 262144);
  cvt_f32_bf16<<<(262144 + 255) / 256, 256, 0, stream>>>(conv2_w, C2WB, 262144);
  cvt_f32_bf16<<<(32768 + 255) / 256, 256, 0, stream>>>(d1_w1, D1W1B, 32768);
  cvt_f32_bf16<<<(32768 + 255) / 256, 256, 0, stream>>>(d2_w1, D2W1B, 32768);
  build_tcs<<<(128 * L_ + 255) / 256, 256, 0, stream>>>(TCS);
  build_basis<<<(L_ * 128 + 255) / 256, 256, 0, stream>>>(BASIS);
  transpose_w<<<dim3(8, 512, 4), 256, 0, stream>>>(w_real, WTR);
  transpose_w<<<dim3(8, 512, 4), 256, 0, stream>>>(w_imag, WTI);
  transpose_x<<<dim3(8, 24, 16), 256, 0, stream>>>(x, XT);

  // --- forward DFT: QT[b*512+d][c] = sum_l xt[bd][l]*tcs[c][l]  (c<64 re, >=64 im) ---
  gemm128<false, false, false, false><<<dim3(64, 1, 1), 256, 0, stream>>>(
      XT, L_, 0, TCS, L_, 0, nullptr, nullptr, 0, 0, QT, 128, 0, L_);
  transpose_q<<<dim3(2, 128), 256, 0, stream>>>(QT, QRI);   // -> QRI[c][bd]

  // --- per-mode complex matmul (all 64 modes, one launch) ---
  mode_gemm<<<dim3(64, 8), 256, 0, stream>>>(QRI, QRI + 64 * B_ * D_, WTR, WTI, OUTM);

  // --- inverse DFT + residual: x1 = x + irfft (bf16 out) ---
  gemm128<false, false, true, false><<<dim3(12, 4, 16), 256, 0, stream>>>(
      BASIS, 128, 0, OUTM, 128, (long)D_ * 128, nullptr,
      x, D_, (long)L_ * D_, X1B, D_, (long)L_ * D_, 128);

  // --- decomp 1 ---
  gemm128<true, true, false, false><<<dim3(192, 2, 1), 256, 0, stream>>>(
      X1B, D_, 0, D1W1B, D_, 0, d1_b1, nullptr, 0, 0, H, HID, 0, D_);
  gates_kernel<<<6144, 256, 0, stream>>>(H, d1_w2, d1_b2, G, B_ * L_);
  combine_kernel<false, true><<<dim3(24, 16), 512, 0, stream>>>(X1B, G, nullptr, X2B);

  // --- FFN, 4 row-chunks of 6144 (Y1C aliases dead XT; ZB aliases dead QT/OUTM/X1B) ---
  for (int rc = 0; rc < 4; ++rc) {
    const short* Ain = X2B + (long)rc * 6144 * D_;
    gemm128<true, false, false, false><<<dim3(48, 16, 1), 256, 0, stream>>>(
        Ain, D_, 0, C1WB, D_, 0, nullptr, nullptr, 0, 0, Y1C, DFF_, 0, D_);
    gemm128<false, false, true, true><<<dim3(48, 4, 1), 256, 0, stream>>>(
        Y1C, DFF_, 0, C2WB, DFF_, 0, nullptr, Ain, D_, 0,
        ZB + (long)rc * 6144 * D_, D_, 0, DFF_);
  }

  // --- decomp 2 -> d_out ---
  gemm128<true, true, false, false><<<dim3(192, 2, 1), 256, 0, stream>>>(
      ZB, D_, 0, D2W1B, D_, 0, d2_b1, nullptr, 0, 0, H, HID, 0, D_);
  gates_kernel<<<6144, 256, 0, stream>>>(H, d2_w2, d2_b2, G, B_ * L_);
  combine_kernel<true, false><<<dim3(24, 16), 512, 0, stream>>>(ZB, G, OUT, nullptr);
}

// Round 4
// 634.022 us; speedup vs baseline: 1.1034x; 1.1034x over previous
//
#include <hip/hip_runtime.h>

#define B_   16
#define L_   1536
#define D_   512
#define DFF_ 2048
#define NM   64
#define HID  256

typedef short short8  __attribute__((ext_vector_type(8)));
typedef short short4v __attribute__((ext_vector_type(4)));
typedef float f32x4   __attribute__((ext_vector_type(4)));

__device__ __forceinline__ float b2f(short s) {
  unsigned int u = ((unsigned int)(unsigned short)s) << 16;
  float f; __builtin_memcpy(&f, &u, 4); return f;
}
__device__ __forceinline__ short f2b(float f) {
  unsigned int u; __builtin_memcpy(&u, &f, 4);
  u += 0x7fffu + ((u >> 16) & 1u);
  return (short)(u >> 16);
}
__device__ __forceinline__ f32x4 zero4() {
  f32x4 v; v[0]=0.f; v[1]=0.f; v[2]=0.f; v[3]=0.f; return v;
}

#define MFMA(a,b,c) __builtin_amdgcn_mfma_f32_16x16x32_bf16((a),(b),(c),0,0,0)
// XOR-swizzled LDS offset (shorts) for 64-short rows: row*64 + (grp^(row&7))*8
#define SWZ(row, grp) (((row) << 6) + ((((grp) ^ ((row) & 7))) << 3))
// async 16B/lane global->LDS (m97: width 16 => global_load_lds_dwordx4)
#define GLDS16(gp, lp) __builtin_amdgcn_global_load_lds( \
    (const __attribute__((address_space(1))) void*)(gp), \
    (__attribute__((address_space(3))) void*)(lp), 16, 0, 0)

// ---------------- guard: zero output (ws too small diagnostic) ----------------
__global__ __launch_bounds__(256) void zero_out(float* __restrict__ o, int n) {
  int i = blockIdx.x * 256 + threadIdx.x;
  if (i < n) o[i] = 0.f;
}

// ---------------- fp32 -> bf16 convert ----------------
__global__ __launch_bounds__(256) void cvt_f32_bf16(const float* __restrict__ s,
                                                    short* __restrict__ d, int n4) {
  int i = blockIdx.x * 256 + threadIdx.x;
  if (i >= n4) return;
  f32x4 v = ((const f32x4*)s)[i];
  short4v o;
  #pragma unroll
  for (int j = 0; j < 4; ++j) o[j] = f2b(v[j]);
  ((short4v*)d)[i] = o;
}

// ---------------- DFT tables ----------------
// tcs[m][l], m<64: cos(2pi m l/L); m in 64..127: -sin(2pi (m-64) l/L)
__global__ __launch_bounds__(256) void build_tcs(short* __restrict__ tcs) {
  int i = blockIdx.x * 256 + threadIdx.x;
  if (i >= 128 * L_) return;
  int m = i / L_, l = i - m * L_;
  int mm = (m < 64) ? m : (m - 64);
  int r = (mm * l) % L_;                      // exact integer angle reduction
  float th = (float)r * (6.283185307179586f / (float)L_);
  float s, c; __sincosf(th, &s, &c);
  tcs[i] = f2b((m < 64) ? c : -s);
}
// basis[l][k]: k<64 -> ((k==0?1:2)/L)*cos(2pi k l/L); k>=64 -> (-2/L)*sin(2pi (k-64) l/L)
__global__ __launch_bounds__(256) void build_basis(short* __restrict__ basis) {
  int i = blockIdx.x * 256 + threadIdx.x;
  if (i >= L_ * 128) return;
  int l = i >> 7, k = i & 127;
  int m = (k < 64) ? k : (k - 64);
  int r = (m * l) % L_;
  float th = (float)r * (6.283185307179586f / (float)L_);
  float s, c; __sincosf(th, &s, &c);
  float v = (k < 64) ? ((m == 0) ? 1.f : 2.f) * (1.f / (float)L_) * c
                     : (-2.f / (float)L_) * s;
  basis[i] = f2b(v);
}

// ---------------- w[d][e][m] f32 -> wt[m][e][d] bf16 (16 modes per grid.z) ----------------
__global__ __launch_bounds__(256) void transpose_w(const float* __restrict__ w,
                                                   short* __restrict__ wt) {
  __shared__ float tile[64][17];
  int dc = blockIdx.x, e = blockIdx.y, t = threadIdx.x;
  int mBase = blockIdx.z * 16;
  {
    int dl = t >> 2, mg = t & 3;
    f32x4 v = *(const f32x4*)(w + ((long)(dc * 64 + dl) * 512 + e) * 64 + mBase + mg * 4);
    tile[dl][mg*4+0] = v[0]; tile[dl][mg*4+1] = v[1];
    tile[dl][mg*4+2] = v[2]; tile[dl][mg*4+3] = v[3];
  }
  __syncthreads();
  if (t < 128) {
    int mr = t >> 3, dg = t & 7;
    short8 o;
    #pragma unroll
    for (int j = 0; j < 8; ++j) o[j] = f2b(tile[dg * 8 + j][mr]);
    *(short8*)(wt + ((long)(mBase + mr) * 512 + e) * 512 + dc * 64 + dg * 8) = o;
  }
}

// ---------------- x[b][l][d] f32 -> xt[b][d][l] bf16 ----------------
__global__ __launch_bounds__(256) void transpose_x(const float* __restrict__ x,
                                                   short* __restrict__ xt) {
  __shared__ float tile[64][65];
  int dc = blockIdx.x, lc = blockIdx.y, b = blockIdx.z, t = threadIdx.x;
  const float* xb = x + (long)b * L_ * D_;
  #pragma unroll
  for (int i = 0; i < 4; ++i) {
    int idx = i * 256 + t; int ll = idx >> 4, dg = idx & 15;
    f32x4 v = *(const f32x4*)(xb + (long)(lc * 64 + ll) * D_ + dc * 64 + dg * 4);
    tile[ll][dg*4+0] = v[0]; tile[ll][dg*4+1] = v[1];
    tile[ll][dg*4+2] = v[2]; tile[ll][dg*4+3] = v[3];
  }
  __syncthreads();
  #pragma unroll
  for (int i = 0; i < 2; ++i) {
    int idx = i * 256 + t; int dl = idx >> 3, lg = idx & 7;
    short8 o;
    #pragma unroll
    for (int j = 0; j < 8; ++j) o[j] = f2b(tile[lg * 8 + j][dl]);
    *(short8*)(xt + ((long)b * D_ + dc * 64 + dl) * L_ + lc * 64 + lg * 8) = o;
  }
}

// ---------------- qt (8192 x 128) bf16 -> q (128 x 8192) bf16 ----------------
__global__ __launch_bounds__(256) void transpose_q(const short* __restrict__ in,
                                                   short* __restrict__ out) {
  __shared__ short tile[64][72];
  int ct = blockIdx.x, rt = blockIdx.y, t = threadIdx.x;
  int r0 = rt * 64, c0 = ct * 64;
  #pragma unroll
  for (int i = 0; i < 2; ++i) {
    int idx = i * 256 + t; int r = idx >> 3, g = idx & 7;
    short8 v = *(const short8*)(in + (long)(r0 + r) * 128 + c0 + g * 8);
    #pragma unroll
    for (int j = 0; j < 8; ++j) tile[r][g * 8 + j] = v[j];
  }
  __syncthreads();
  #pragma unroll
  for (int i = 0; i < 2; ++i) {
    int idx = i * 256 + t; int c = idx >> 3, g = idx & 7;
    short8 o;
    #pragma unroll
    for (int j = 0; j < 8; ++j) o[j] = tile[g * 8 + j][c];
    *(short8*)(out + (long)(c0 + c) * 8192 + r0 + g * 8) = o;
  }
}

// ---------------- 64x64-tile bf16 MFMA GEMM (GLDS16 staging) ----------------
// For skinny shapes needing grid saturation. C = act(A*W^T + bias), bf16 row-major out.
template<bool RELU, bool HASBIAS>
__global__ __launch_bounds__(256) void gemm64(
    const short* __restrict__ A, long ldA,
    const short* __restrict__ W, long ldW,
    const float* __restrict__ bias,
    short* __restrict__ outB, long ldC, int K)
{
  __shared__ short lA[64 * 64];
  __shared__ short lW[64 * 64];
  const int t = threadIdx.x, lane = t & 63, wid = t >> 6;
  const int quad = lane >> 4, l15 = lane & 15;
  const int wm = (wid & 1) * 32, wn = (wid >> 1) * 32;
  const long row0 = (long)blockIdx.x * 64, col0 = (long)blockIdx.y * 64;
  const short* Ab = A + row0 * ldA;
  const short* Wb = W + col0 * ldW;

  // 8 chunks of 1KB per matrix; wave w stages chunks {2w,2w+1} of A and W.
  int srcrow[2]; long srcoff[2];
  #pragma unroll
  for (int i = 0; i < 2; ++i) {
    int c = wid * 2 + i;
    int r = c * 8 + (lane >> 3);
    int g = (lane & 7) ^ (r & 7);
    srcrow[i] = r; srcoff[i] = g * 8;
  }

  f32x4 acc[2][2];
  #pragma unroll
  for (int i = 0; i < 2; ++i)
    #pragma unroll
    for (int j = 0; j < 2; ++j) acc[i][j] = zero4();

  for (int k0 = 0; k0 < K; k0 += 64) {
    __syncthreads();
    #pragma unroll
    for (int i = 0; i < 2; ++i) {
      int c = wid * 2 + i;
      GLDS16(Ab + (long)srcrow[i] * ldA + k0 + srcoff[i], lA + c * 512);
      GLDS16(Wb + (long)srcrow[i] * ldW + k0 + srcoff[i], lW + c * 512);
    }
    __syncthreads();
    #pragma unroll
    for (int ks = 0; ks < 2; ++ks) {
      int gq = ks * 4 + quad;
      short8 a0 = *(const short8*)&lA[SWZ(wm + l15, gq)];
      short8 a1 = *(const short8*)&lA[SWZ(wm + 16 + l15, gq)];
      short8 b0 = *(const short8*)&lW[SWZ(wn + l15, gq)];
      short8 b1 = *(const short8*)&lW[SWZ(wn + 16 + l15, gq)];
      acc[0][0] = MFMA(a0, b0, acc[0][0]);
      acc[0][1] = MFMA(a0, b1, acc[0][1]);
      acc[1][0] = MFMA(a1, b0, acc[1][0]);
      acc[1][1] = MFMA(a1, b1, acc[1][1]);
    }
  }
  #pragma unroll
  for (int ni = 0; ni < 2; ++ni) {
    long col = col0 + wn + ni * 16 + l15;
    float bvv = HASBIAS ? bias[col] : 0.f;
    #pragma unroll
    for (int mi = 0; mi < 2; ++mi) {
      #pragma unroll
      for (int r = 0; r < 4; ++r) {
        long row = row0 + wm + mi * 16 + quad * 4 + r;
        float v = acc[mi][ni][r];
        if (HASBIAS) v += bvv;
        if (RELU)    v = fmaxf(v, 0.f);
        outB[row * ldC + col] = f2b(v);
      }
    }
  }
}

// ---------------- 128x128-tile bf16 MFMA GEMM (m97 structure) ----------------
template<bool RELU, bool HASBIAS, bool HASRES, bool RESB>
__global__ __launch_bounds__(256) void gemm128(
    const short* __restrict__ A, long ldA, long Az,
    const short* __restrict__ W, long ldW, long Wz,
    const float* __restrict__ bias,
    const void* __restrict__ res, long ldres, long resZ,
    short* __restrict__ outB, long ldC, long Cz, int K)
{
  __shared__ short lA[128 * 64];
  __shared__ short lW[128 * 64];
  const int t = threadIdx.x, lane = t & 63, wid = t >> 6;
  const int quad = lane >> 4, l15 = lane & 15;
  const int wm = (wid & 1) * 64, wn = (wid >> 1) * 64;
  const long row0 = (long)blockIdx.x * 128, col0 = (long)blockIdx.y * 128;
  const int z = blockIdx.z;
  const short* Ab = A + (long)z * Az + row0 * ldA;
  const short* Wb = W + (long)z * Wz + col0 * ldW;

  int srcrow[4]; long srcoff[4];
  #pragma unroll
  for (int i = 0; i < 4; ++i) {
    int c = wid * 4 + i;
    int r = c * 8 + (lane >> 3);
    int g = (lane & 7) ^ (r & 7);
    srcrow[i] = r; srcoff[i] = g * 8;
  }

  f32x4 acc[4][4];
  #pragma unroll
  for (int i = 0; i < 4; ++i)
    #pragma unroll
    for (int j = 0; j < 4; ++j) acc[i][j] = zero4();

  for (int k0 = 0; k0 < K; k0 += 64) {
    __syncthreads();
    #pragma unroll
    for (int i = 0; i < 4; ++i) {
      int c = wid * 4 + i;
      GLDS16(Ab + (long)srcrow[i] * ldA + k0 + srcoff[i], lA + c * 512);
      GLDS16(Wb + (long)srcrow[i] * ldW + k0 + srcoff[i], lW + c * 512);
    }
    __syncthreads();
    #pragma unroll
    for (int ks = 0; ks < 2; ++ks) {
      int gq = ks * 4 + quad;
      short8 av[4], bv[4];
      #pragma unroll
      for (int mi = 0; mi < 4; ++mi) av[mi] = *(const short8*)&lA[SWZ(wm + mi * 16 + l15, gq)];
      #pragma unroll
      for (int ni = 0; ni < 4; ++ni) bv[ni] = *(const short8*)&lW[SWZ(wn + ni * 16 + l15, gq)];
      #pragma unroll
      for (int mi = 0; mi < 4; ++mi)
        #pragma unroll
        for (int ni = 0; ni < 4; ++ni)
          acc[mi][ni] = MFMA(av[mi], bv[ni], acc[mi][ni]);
    }
  }
  #pragma unroll
  for (int ni = 0; ni < 4; ++ni) {
    long col = col0 + wn + ni * 16 + l15;
    float bvv = HASBIAS ? bias[col] : 0.f;
    #pragma unroll
    for (int mi = 0; mi < 4; ++mi) {
      #pragma unroll
      for (int r = 0; r < 4; ++r) {
        long row = row0 + wm + mi * 16 + quad * 4 + r;
        float v = acc[mi][ni][r];
        if (HASBIAS) v += bvv;
        if (RELU)    v = fmaxf(v, 0.f);
        if (HASRES) {
          long ro = (long)z * resZ + row * ldres + col;
          v += RESB ? b2f(((const short*)res)[ro]) : ((const float*)res)[ro];
        }
        outB[(long)z * Cz + row * ldC + col] = f2b(v);
      }
    }
  }
}

// ---------------- per-mode complex GEMM ----------------
__global__ __launch_bounds__(256) void mode_gemm(
    const short* __restrict__ qr, const short* __restrict__ qi,
    const short* __restrict__ wr, const short* __restrict__ wi,
    short* __restrict__ outm)
{
  __shared__ short lqr[16 * 64], lqi[16 * 64], lwr[64 * 64], lwi[64 * 64];
  const int m = blockIdx.x, en = blockIdx.y;
  const int t = threadIdx.x, lane = t & 63, wid = t >> 6;
  const int quad = lane >> 4, l15 = lane & 15;
  const short* qrb = qr + (long)m * (B_ * D_);
  const short* qib = qi + (long)m * (B_ * D_);
  const short* wrb = wr + (long)m * (D_ * D_) + (long)en * 64 * D_;
  const short* wib = wi + (long)m * (D_ * D_) + (long)en * 64 * D_;
  f32x4 accr = zero4(), acci = zero4();
  for (int k0 = 0; k0 < D_; k0 += 64) {
    __syncthreads();
    {
      int idx = t & 127; int r = idx >> 3, cg = idx & 7;
      const short* src = (t < 128 ? qrb : qib) + r * D_ + k0 + cg * 8;
      short* dst = (t < 128) ? lqr : lqi;
      *(short8*)&dst[SWZ(r, cg)] = *(const short8*)src;
    }
    #pragma unroll
    for (int i = 0; i < 4; ++i) {
      int idx = i * 256 + t;
      int which = idx >> 9, idx2 = idx & 511;
      int r = idx2 >> 3, cg = idx2 & 7;
      const short* src = (which ? wib : wrb) + r * D_ + k0 + cg * 8;
      short* dst = which ? lwi : lwr;
      *(short8*)&dst[SWZ(r, cg)] = *(const short8*)src;
    }
    __syncthreads();
    #pragma unroll
    for (int ks = 0; ks < 2; ++ks) {
      int gq = ks * 4 + quad;
      short8 ar = *(const short8*)&lqr[SWZ(l15, gq)];
      short8 ai = *(const short8*)&lqi[SWZ(l15, gq)];
      short8 br = *(const short8*)&lwr[SWZ(wid * 16 + l15, gq)];
      short8 bi = *(const short8*)&lwi[SWZ(wid * 16 + l15, gq)];
      short8 nai;
      #pragma unroll
      for (int j = 0; j < 8; ++j) nai[j] = (short)(ai[j] ^ (short)0x8000);
      accr = MFMA(ar, br, accr);
      accr = MFMA(nai, bi, accr);   // - qi*wi
      acci = MFMA(ar, bi, acci);
      acci = MFMA(ai, br, acci);
    }
  }
  #pragma unroll
  for (int r = 0; r < 4; ++r) {
    int bb = quad * 4 + r;
    long e = (long)en * 64 + wid * 16 + l15;
    long base = ((long)bb * D_ + e) * 128 + m;
    outm[base]      = f2b(accr[r]);
    outm[base + 64] = f2b(acci[r]);
  }
}

// ---------------- 3-expert gates: softmax(h @ w2^T + b2) ----------------
__global__ __launch_bounds__(256) void gates_kernel(
    const short* __restrict__ h, const float* __restrict__ w2,
    const float* __restrict__ b2, float* __restrict__ g, int rows)
{
  int wid = threadIdx.x >> 6, lane = threadIdx.x & 63;
  int row = blockIdx.x * 4 + wid;
  if (row >= rows) return;
  const short* hr = h + (long)row * HID;
  short4v hh = *(const short4v*)(hr + lane * 4);
  float hv[4];
  #pragma unroll
  for (int j = 0; j < 4; ++j) hv[j] = b2f(hh[j]);
  float lg[3];
  #pragma unroll
  for (int e = 0; e < 3; ++e) {
    const float* wrow = w2 + e * HID + lane * 4;
    float p = hv[0] * wrow[0] + hv[1] * wrow[1] + hv[2] * wrow[2] + hv[3] * wrow[3];
    #pragma unroll
    for (int off = 32; off >= 1; off >>= 1) p += __shfl_xor(p, off);
    lg[e] = p + b2[e];
  }
  float mx = fmaxf(lg[0], fmaxf(lg[1], lg[2]));
  float e0 = __expf(lg[0] - mx), e1 = __expf(lg[1] - mx), e2 = __expf(lg[2] - mx);
  float inv = 1.f / (e0 + e1 + e2);
  float gv = (lane == 0) ? e0 * inv : (lane == 1) ? e1 * inv : e2 * inv;
  if (lane < 3) g[(long)row * 3 + lane] = gv;
}

// ---------------- seasonal combine: out = x - sum_e gate_e * avgpool_{3,5,7}(x) ----------------
template<bool OUTF, bool WRITEB>
__global__ __launch_bounds__(512) void combine_kernel(
    const short* __restrict__ xin, const float* __restrict__ g,
    float* __restrict__ outf, short* __restrict__ outb)
{
  int lc = blockIdx.x, b = blockIdx.y, d = threadIdx.x;
  int l0 = lc * 64;
  const short* xb = xin + (long)b * L_ * D_ + d;
  const float* gb = g + (long)b * L_ * 3;
  float win[7];
  #pragma unroll
  for (int j = 0; j < 6; ++j) {
    int l = l0 - 3 + j;
    win[j] = (l >= 0 && l < L_) ? b2f(xb[(long)l * D_]) : 0.f;
  }
  for (int i = 0; i < 64; ++i) {
    int lcn = l0 + i;
    int lr = lcn + 3;
    win[6] = (lr < L_) ? b2f(xb[(long)lr * D_]) : 0.f;
    float s3 = win[2] + win[3] + win[4];
    float s5 = s3 + win[1] + win[5];
    float s7 = s5 + win[0] + win[6];
    float g0 = gb[lcn * 3 + 0], g1 = gb[lcn * 3 + 1], g2 = gb[lcn * 3 + 2];
    float trend = g0 * s3 * (1.f / 3.f) + g1 * s5 * (1.f / 5.f) + g2 * s7 * (1.f / 7.f);
    float v = win[3] - trend;
    long o = ((long)b * L_ + lcn) * D_ + d;
    if (OUTF)   outf[o] = v;
    if (WRITEB) outb[o] = f2b(v);
    #pragma unroll
    for (int j = 0; j < 6; ++j) win[j] = win[j + 1];
  }
}

extern "C" void kernel_launch(void* const* d_in, const int* in_sizes, int n_in,
                              void* d_out, int out_size, void* d_ws, size_t ws_size,
                              hipStream_t stream) {
  const float* x       = (const float*)d_in[0];
  const float* w_real  = (const float*)d_in[1];
  const float* w_imag  = (const float*)d_in[2];
  const float* conv1_w = (const float*)d_in[3];
  const float* conv2_w = (const float*)d_in[4];
  const float* d1_w1   = (const float*)d_in[5];
  const float* d1_b1   = (const float*)d_in[6];
  const float* d1_w2   = (const float*)d_in[7];
  const float* d1_b2   = (const float*)d_in[8];
  const float* d2_w1   = (const float*)d_in[9];
  const float* d2_b1   = (const float*)d_in[10];
  const float* d2_w2   = (const float*)d_in[11];
  const float* d2_b2   = (const float*)d_in[12];
  float* OUT = (float*)d_out;

  // Two arena layouts:
  //   BIG   (ws >= 144,703,488): full-M FFN, Y1 = 100.7 MB aliasing dead prep region.
  //   SMALL (ws >= 98,566,144; known ws >= 115.3 MB from R2): 2-chunk FFN.
  const size_t REQ_BIG = 144703488, REQ_SMALL = 98566144;
  if (ws_size < REQ_SMALL) {
    zero_out<<<(out_size + 255) / 256, 256, 0, stream>>>(OUT, out_size);
    return;
  }
  const bool big = (ws_size >= REQ_BIG);

  char* ws = (char*)d_ws;
  short* C1WB  = (short*)(ws + 0);          //  2,097,152
  short* C2WB  = (short*)(ws + 2097152);    //  2,097,152
  short* D1W1B = (short*)(ws + 4194304);    //    262,144
  short* D2W1B = (short*)(ws + 4456448);    //    262,144
  short* TCS   = (short*)(ws + 4718592);    //    393,216
  short* BASIS = (short*)(ws + 5111808);    //    393,216
  float* G     = (float*)(ws + 5505024);    //    294,912 (pad -> 6,291,456)
  short* XT    = (short*)(ws + 6291456);    // 25,165,824 [dead after fwdDFT]
  short* QRI   = XT;                        //  2,097,152 [alias; dead after modes]
  short* Y1    = XT;                        // big:100.7MB / small:50.3MB [FFN phase]
  short* QT    = (short*)(ws + 31457280);   //  2,097,152 [dead after transpose_q]
  short* OUTM  = (short*)(ws + 33554432);   //  2,097,152 [dead after invDFT]
  short* WTR   = (short*)(ws + 35651584);   // 33,554,432 [dead after modes]
  short* X1B   = WTR;                       // 25,165,824 [alias; ends 60,817,408; dead after combine1]
  short* WTI   = (short*)(ws + 69206016);   // 33,554,432 [dead after modes]
  // X2B: live combine1 -> end; FFN2 writes it in place (ZB == X2B).
  short* X2B   = (short*)(ws + (big ? 106954752 : 60817408));   // 25,165,824
  short* H     = (short*)(ws + (big ? 132120576 : 85983232));   // 12,582,912

  // --- weight prep ---
  cvt_f32_bf16<<<(262144 + 255) / 256, 256, 0, stream>>>(conv1_w, C1WB, 262144);
  cvt_f32_bf16<<<(262144 + 255) / 256, 256, 0, stream>>>(conv2_w, C2WB, 262144);
  cvt_f32_bf16<<<(32768 + 255) / 256, 256, 0, stream>>>(d1_w1, D1W1B, 32768);
  cvt_f32_bf16<<<(32768 + 255) / 256, 256, 0, stream>>>(d2_w1, D2W1B, 32768);
  build_tcs<<<(128 * L_ + 255) / 256, 256, 0, stream>>>(TCS);
  build_basis<<<(L_ * 128 + 255) / 256, 256, 0, stream>>>(BASIS);
  transpose_w<<<dim3(8, 512, 4), 256, 0, stream>>>(w_real, WTR);
  transpose_w<<<dim3(8, 512, 4), 256, 0, stream>>>(w_imag, WTI);
  transpose_x<<<dim3(8, 24, 16), 256, 0, stream>>>(x, XT);

  // --- forward DFT: QT[bd][c] = sum_l xt[bd][l]*tcs[c][l]  (256 blocks) ---
  gemm64<false, false><<<dim3(128, 2), 256, 0, stream>>>(
      XT, L_, TCS, L_, nullptr, QT, 128, L_);
  transpose_q<<<dim3(2, 128), 256, 0, stream>>>(QT, QRI);   // -> QRI[c][bd]

  // --- per-mode complex matmul ---
  mode_gemm<<<dim3(64, 8), 256, 0, stream>>>(QRI, QRI + 64 * B_ * D_, WTR, WTI, OUTM);

  // --- inverse DFT + residual: x1 = x + irfft (768 blocks) ---
  gemm128<false, false, true, false><<<dim3(12, 4, 16), 256, 0, stream>>>(
      BASIS, 128, 0, OUTM, 128, (long)D_ * 128, nullptr,
      x, D_, (long)L_ * D_, X1B, D_, (long)L_ * D_, 128);

  // --- decomp 1 (1536 blocks) ---
  gemm64<true, true><<<dim3(384, 4), 256, 0, stream>>>(
      X1B, D_, D1W1B, D_, d1_b1, H, HID, D_);
  gates_kernel<<<6144, 256, 0, stream>>>(H, d1_w2, d1_b2, G, B_ * L_);
  combine_kernel<false, true><<<dim3(24, 16), 512, 0, stream>>>(X1B, G, nullptr, X2B);

  // --- FFN: big = single full-M pass; small = 2 row-chunks. FFN2 in-place into X2B. ---
  {
    const int nchunk = big ? 1 : 2;
    const long rows = big ? 24576 : 12288;
    for (int rc = 0; rc < nchunk; ++rc) {
      short* Ain = X2B + (long)rc * rows * D_;
      gemm128<true, false, false, false><<<dim3(rows / 128, 16, 1), 256, 0, stream>>>(
          Ain, D_, 0, C1WB, D_, 0, nullptr, nullptr, 0, 0, Y1, DFF_, 0, D_);
      gemm128<false, false, true, true><<<dim3(rows / 128, 4, 1), 256, 0, stream>>>(
          Y1, DFF_, 0, C2WB, DFF_, 0, nullptr, Ain, D_, 0, Ain, D_, 0, DFF_);
    }
  }

  // --- decomp 2 -> d_out (X2B now holds z = x2 + FFN(x2)) ---
  gemm64<true, true><<<dim3(384, 4), 256, 0, stream>>>(
      X2B, D_, D2W1B, D_, d2_b1, H, HID, D_);
  gates_kernel<<<6144, 256, 0, stream>>>(H, d2_w2, d2_b2, G, B_ * L_);
  combine_kernel<true, false><<<dim3(24, 16), 512, 0, stream>>>(X2B, G, OUT, nullptr);
}

// Round 5
// 624.571 us; speedup vs baseline: 1.1201x; 1.0151x over previous
//
#include <hip/hip_runtime.h>

#define B_   16
#define L_   1536
#define D_   512
#define DFF_ 2048
#define NM   64
#define HID  256

typedef short short8  __attribute__((ext_vector_type(8)));
typedef short short4v __attribute__((ext_vector_type(4)));
typedef float f32x4   __attribute__((ext_vector_type(4)));

__device__ __forceinline__ float b2f(short s) {
  unsigned int u = ((unsigned int)(unsigned short)s) << 16;
  float f; __builtin_memcpy(&f, &u, 4); return f;
}
__device__ __forceinline__ short f2b(float f) {
  unsigned int u; __builtin_memcpy(&u, &f, 4);
  u += 0x7fffu + ((u >> 16) & 1u);
  return (short)(u >> 16);
}
__device__ __forceinline__ f32x4 zero4() {
  f32x4 v; v[0]=0.f; v[1]=0.f; v[2]=0.f; v[3]=0.f; return v;
}

#define MFMA(a,b,c) __builtin_amdgcn_mfma_f32_16x16x32_bf16((a),(b),(c),0,0,0)
// XOR-swizzled LDS offset (shorts) for 64-short rows: row*64 + (grp^(row&7))*8
#define SWZ(row, grp) (((row) << 6) + ((((grp) ^ ((row) & 7))) << 3))
// async 16B/lane global->LDS (m97: width 16 => global_load_lds_dwordx4)
#define GLDS16(gp, lp) __builtin_amdgcn_global_load_lds( \
    (const __attribute__((address_space(1))) void*)(gp), \
    (__attribute__((address_space(3))) void*)(lp), 16, 0, 0)

// ---------------- guard: zero output (ws too small diagnostic) ----------------
__global__ __launch_bounds__(256) void zero_out(float* __restrict__ o, int n) {
  int i = blockIdx.x * 256 + threadIdx.x;
  if (i < n) o[i] = 0.f;
}

// ---------------- fused prep: 4x f32->bf16 convert + DFT tables ----------------
// blocks [0,1024): conv1 | [1024,2048): conv2 | [2048,2176): d1w1 |
// [2176,2304): d2w1 | [2304,3072): tcs | [3072,3840): basis
__global__ __launch_bounds__(256) void prep_all(
    const float* __restrict__ conv1_w, const float* __restrict__ conv2_w,
    const float* __restrict__ d1_w1,  const float* __restrict__ d2_w1,
    short* __restrict__ c1, short* __restrict__ c2,
    short* __restrict__ dw1, short* __restrict__ dw2,
    short* __restrict__ tcs, short* __restrict__ basis)
{
  int blk = blockIdx.x;
  if (blk < 2304) {   // converts: pick source/dest
    const float* s; short* d; int i;
    if (blk < 1024)      { s = conv1_w; d = c1;  i = blk * 256 + threadIdx.x; }
    else if (blk < 2048) { s = conv2_w; d = c2;  i = (blk - 1024) * 256 + threadIdx.x; }
    else if (blk < 2176) { s = d1_w1;   d = dw1; i = (blk - 2048) * 256 + threadIdx.x; }
    else                 { s = d2_w1;   d = dw2; i = (blk - 2176) * 256 + threadIdx.x; }
    f32x4 v = ((const f32x4*)s)[i];
    short4v o;
    #pragma unroll
    for (int j = 0; j < 4; ++j) o[j] = f2b(v[j]);
    ((short4v*)d)[i] = o;
    return;
  }
  if (blk < 3072) {   // tcs[m][l], m<64: cos; m>=64: -sin
    int i = (blk - 2304) * 256 + threadIdx.x;
    int m = i / L_, l = i - m * L_;
    int mm = (m < 64) ? m : (m - 64);
    int r = (mm * l) % L_;
    float th = (float)r * (6.283185307179586f / (float)L_);
    float s, c; __sincosf(th, &s, &c);
    tcs[i] = f2b((m < 64) ? c : -s);
    return;
  }
  {   // basis[l][k]
    int i = (blk - 3072) * 256 + threadIdx.x;
    int l = i >> 7, k = i & 127;
    int m = (k < 64) ? k : (k - 64);
    int r = (m * l) % L_;
    float th = (float)r * (6.283185307179586f / (float)L_);
    float s, c; __sincosf(th, &s, &c);
    float v = (k < 64) ? ((m == 0) ? 1.f : 2.f) * (1.f / (float)L_) * c
                       : (-2.f / (float)L_) * s;
    basis[i] = f2b(v);
  }
}

// ---------------- w[d][e][m] f32 -> wt[m][e][d] bf16; z<4 real, z>=4 imag ----------------
__global__ __launch_bounds__(256) void transpose_w(
    const float* __restrict__ wre, const float* __restrict__ wim,
    short* __restrict__ wtr, short* __restrict__ wti)
{
  __shared__ float tile[64][17];
  int dc = blockIdx.x, e = blockIdx.y, t = threadIdx.x;
  int zz = blockIdx.z;
  const float* w = (zz < 4) ? wre : wim;
  short* wt      = (zz < 4) ? wtr : wti;
  int mBase = (zz & 3) * 16;
  {
    int dl = t >> 2, mg = t & 3;
    f32x4 v = *(const f32x4*)(w + ((long)(dc * 64 + dl) * 512 + e) * 64 + mBase + mg * 4);
    tile[dl][mg*4+0] = v[0]; tile[dl][mg*4+1] = v[1];
    tile[dl][mg*4+2] = v[2]; tile[dl][mg*4+3] = v[3];
  }
  __syncthreads();
  if (t < 128) {
    int mr = t >> 3, dg = t & 7;
    short8 o;
    #pragma unroll
    for (int j = 0; j < 8; ++j) o[j] = f2b(tile[dg * 8 + j][mr]);
    *(short8*)(wt + ((long)(mBase + mr) * 512 + e) * 512 + dc * 64 + dg * 8) = o;
  }
}

// ---------------- x[b][l][d] f32 -> xt[b][d][l] bf16 ----------------
__global__ __launch_bounds__(256) void transpose_x(const float* __restrict__ x,
                                                   short* __restrict__ xt) {
  __shared__ float tile[64][65];
  int dc = blockIdx.x, lc = blockIdx.y, b = blockIdx.z, t = threadIdx.x;
  const float* xb = x + (long)b * L_ * D_;
  #pragma unroll
  for (int i = 0; i < 4; ++i) {
    int idx = i * 256 + t; int ll = idx >> 4, dg = idx & 15;
    f32x4 v = *(const f32x4*)(xb + (long)(lc * 64 + ll) * D_ + dc * 64 + dg * 4);
    tile[ll][dg*4+0] = v[0]; tile[ll][dg*4+1] = v[1];
    tile[ll][dg*4+2] = v[2]; tile[ll][dg*4+3] = v[3];
  }
  __syncthreads();
  #pragma unroll
  for (int i = 0; i < 2; ++i) {
    int idx = i * 256 + t; int dl = idx >> 3, lg = idx & 7;
    short8 o;
    #pragma unroll
    for (int j = 0; j < 8; ++j) o[j] = f2b(tile[lg * 8 + j][dl]);
    *(short8*)(xt + ((long)b * D_ + dc * 64 + dl) * L_ + lc * 64 + lg * 8) = o;
  }
}

// ---------------- 64x64-tile bf16 MFMA GEMM (GLDS16 staging, generic store) ----------------
// C = act(A*W^T + bias); out addr = row*csr + col*csc (bf16).
template<bool RELU, bool HASBIAS>
__global__ __launch_bounds__(256) void gemm64(
    const short* __restrict__ A, long ldA,
    const short* __restrict__ W, long ldW,
    const float* __restrict__ bias,
    short* __restrict__ outB, long csr, long csc, int K)
{
  __shared__ short lA[64 * 64];
  __shared__ short lW[64 * 64];
  const int t = threadIdx.x, lane = t & 63, wid = t >> 6;
  const int quad = lane >> 4, l15 = lane & 15;
  const int wm = (wid & 1) * 32, wn = (wid >> 1) * 32;
  const long row0 = (long)blockIdx.x * 64, col0 = (long)blockIdx.y * 64;
  const short* Ab = A + row0 * ldA;
  const short* Wb = W + col0 * ldW;

  int srcrow[2]; long srcoff[2];
  #pragma unroll
  for (int i = 0; i < 2; ++i) {
    int c = wid * 2 + i;
    int r = c * 8 + (lane >> 3);
    int g = (lane & 7) ^ (r & 7);
    srcrow[i] = r; srcoff[i] = g * 8;
  }

  f32x4 acc[2][2];
  #pragma unroll
  for (int i = 0; i < 2; ++i)
    #pragma unroll
    for (int j = 0; j < 2; ++j) acc[i][j] = zero4();

  for (int k0 = 0; k0 < K; k0 += 64) {
    __syncthreads();
    #pragma unroll
    for (int i = 0; i < 2; ++i) {
      int c = wid * 2 + i;
      GLDS16(Ab + (long)srcrow[i] * ldA + k0 + srcoff[i], lA + c * 512);
      GLDS16(Wb + (long)srcrow[i] * ldW + k0 + srcoff[i], lW + c * 512);
    }
    __syncthreads();
    #pragma unroll
    for (int ks = 0; ks < 2; ++ks) {
      int gq = ks * 4 + quad;
      short8 a0 = *(const short8*)&lA[SWZ(wm + l15, gq)];
      short8 a1 = *(const short8*)&lA[SWZ(wm + 16 + l15, gq)];
      short8 b0 = *(const short8*)&lW[SWZ(wn + l15, gq)];
      short8 b1 = *(const short8*)&lW[SWZ(wn + 16 + l15, gq)];
      acc[0][0] = MFMA(a0, b0, acc[0][0]);
      acc[0][1] = MFMA(a0, b1, acc[0][1]);
      acc[1][0] = MFMA(a1, b0, acc[1][0]);
      acc[1][1] = MFMA(a1, b1, acc[1][1]);
    }
  }
  #pragma unroll
  for (int ni = 0; ni < 2; ++ni) {
    long col = col0 + wn + ni * 16 + l15;
    float bvv = HASBIAS ? bias[col] : 0.f;
    #pragma unroll
    for (int mi = 0; mi < 2; ++mi) {
      #pragma unroll
      for (int r = 0; r < 4; ++r) {
        long row = row0 + wm + mi * 16 + quad * 4 + r;
        float v = acc[mi][ni][r];
        if (HASBIAS) v += bvv;
        if (RELU)    v = fmaxf(v, 0.f);
        outB[row * csr + col * csc] = f2b(v);
      }
    }
  }
}

// ---------------- 128x128-tile bf16 MFMA GEMM (m97 structure) ----------------
template<bool RELU, bool HASBIAS, bool HASRES, bool RESB>
__global__ __launch_bounds__(256) void gemm128(
    const short* __restrict__ A, long ldA, long Az,
    const short* __restrict__ W, long ldW, long Wz,
    const float* __restrict__ bias,
    const void* __restrict__ res, long ldres, long resZ,
    short* __restrict__ outB, long ldC, long Cz, int K)
{
  __shared__ short lA[128 * 64];
  __shared__ short lW[128 * 64];
  const int t = threadIdx.x, lane = t & 63, wid = t >> 6;
  const int quad = lane >> 4, l15 = lane & 15;
  const int wm = (wid & 1) * 64, wn = (wid >> 1) * 64;
  const long row0 = (long)blockIdx.x * 128, col0 = (long)blockIdx.y * 128;
  const int z = blockIdx.z;
  const short* Ab = A + (long)z * Az + row0 * ldA;
  const short* Wb = W + (long)z * Wz + col0 * ldW;

  int srcrow[4]; long srcoff[4];
  #pragma unroll
  for (int i = 0; i < 4; ++i) {
    int c = wid * 4 + i;
    int r = c * 8 + (lane >> 3);
    int g = (lane & 7) ^ (r & 7);
    srcrow[i] = r; srcoff[i] = g * 8;
  }

  f32x4 acc[4][4];
  #pragma unroll
  for (int i = 0; i < 4; ++i)
    #pragma unroll
    for (int j = 0; j < 4; ++j) acc[i][j] = zero4();

  for (int k0 = 0; k0 < K; k0 += 64) {
    __syncthreads();
    #pragma unroll
    for (int i = 0; i < 4; ++i) {
      int c = wid * 4 + i;
      GLDS16(Ab + (long)srcrow[i] * ldA + k0 + srcoff[i], lA + c * 512);
      GLDS16(Wb + (long)srcrow[i] * ldW + k0 + srcoff[i], lW + c * 512);
    }
    __syncthreads();
    #pragma unroll
    for (int ks = 0; ks < 2; ++ks) {
      int gq = ks * 4 + quad;
      short8 av[4], bv[4];
      #pragma unroll
      for (int mi = 0; mi < 4; ++mi) av[mi] = *(const short8*)&lA[SWZ(wm + mi * 16 + l15, gq)];
      #pragma unroll
      for (int ni = 0; ni < 4; ++ni) bv[ni] = *(const short8*)&lW[SWZ(wn + ni * 16 + l15, gq)];
      #pragma unroll
      for (int mi = 0; mi < 4; ++mi)
        #pragma unroll
        for (int ni = 0; ni < 4; ++ni)
          acc[mi][ni] = MFMA(av[mi], bv[ni], acc[mi][ni]);
    }
  }
  #pragma unroll
  for (int ni = 0; ni < 4; ++ni) {
    long col = col0 + wn + ni * 16 + l15;
    float bvv = HASBIAS ? bias[col] : 0.f;
    #pragma unroll
    for (int mi = 0; mi < 4; ++mi) {
      #pragma unroll
      for (int r = 0; r < 4; ++r) {
        long row = row0 + wm + mi * 16 + quad * 4 + r;
        float v = acc[mi][ni][r];
        if (HASBIAS) v += bvv;
        if (RELU)    v = fmaxf(v, 0.f);
        if (HASRES) {
          long ro = (long)z * resZ + row * ldres + col;
          v += RESB ? b2f(((const short*)res)[ro]) : ((const float*)res)[ro];
        }
        outB[(long)z * Cz + row * ldC + col] = f2b(v);
      }
    }
  }
}

// ---------------- per-mode complex GEMM ----------------
__global__ __launch_bounds__(256) void mode_gemm(
    const short* __restrict__ qr, const short* __restrict__ qi,
    const short* __restrict__ wr, const short* __restrict__ wi,
    short* __restrict__ outm)
{
  __shared__ short lqr[16 * 64], lqi[16 * 64], lwr[64 * 64], lwi[64 * 64];
  const int m = blockIdx.x, en = blockIdx.y;
  const int t = threadIdx.x, lane = t & 63, wid = t >> 6;
  const int quad = lane >> 4, l15 = lane & 15;
  const short* qrb = qr + (long)m * (B_ * D_);
  const short* qib = qi + (long)m * (B_ * D_);
  const short* wrb = wr + (long)m * (D_ * D_) + (long)en * 64 * D_;
  const short* wib = wi + (long)m * (D_ * D_) + (long)en * 64 * D_;
  f32x4 accr = zero4(), acci = zero4();
  for (int k0 = 0; k0 < D_; k0 += 64) {
    __syncthreads();
    {
      int idx = t & 127; int r = idx >> 3, cg = idx & 7;
      const short* src = (t < 128 ? qrb : qib) + r * D_ + k0 + cg * 8;
      short* dst = (t < 128) ? lqr : lqi;
      *(short8*)&dst[SWZ(r, cg)] = *(const short8*)src;
    }
    #pragma unroll
    for (int i = 0; i < 4; ++i) {
      int idx = i * 256 + t;
      int which = idx >> 9, idx2 = idx & 511;
      int r = idx2 >> 3, cg = idx2 & 7;
      const short* src = (which ? wib : wrb) + r * D_ + k0 + cg * 8;
      short* dst = which ? lwi : lwr;
      *(short8*)&dst[SWZ(r, cg)] = *(const short8*)src;
    }
    __syncthreads();
    #pragma unroll
    for (int ks = 0; ks < 2; ++ks) {
      int gq = ks * 4 + quad;
      short8 ar = *(const short8*)&lqr[SWZ(l15, gq)];
      short8 ai = *(const short8*)&lqi[SWZ(l15, gq)];
      short8 br = *(const short8*)&lwr[SWZ(wid * 16 + l15, gq)];
      short8 bi = *(const short8*)&lwi[SWZ(wid * 16 + l15, gq)];
      short8 nai;
      #pragma unroll
      for (int j = 0; j < 8; ++j) nai[j] = (short)(ai[j] ^ (short)0x8000);
      accr = MFMA(ar, br, accr);
      accr = MFMA(nai, bi, accr);   // - qi*wi
      acci = MFMA(ar, bi, acci);
      acci = MFMA(ai, br, acci);
    }
  }
  #pragma unroll
  for (int r = 0; r < 4; ++r) {
    int bb = quad * 4 + r;
    long e = (long)en * 64 + wid * 16 + l15;
    long base = ((long)bb * D_ + e) * 128 + m;
    outm[base]      = f2b(accr[r]);
    outm[base + 64] = f2b(acci[r]);
  }
}

// ---------------- fused gates + seasonal combine ----------------
// Per block (lc,b): compute softmax gates for its 64 positions from H (wave-
// shuffle reduce, same math as the old gates_kernel), then
// out = x - sum_e gate_e * avgpool_{3,5,7}(x).
template<bool OUTF, bool WRITEB>
__global__ __launch_bounds__(512) void combine_kernel(
    const short* __restrict__ xin, const short* __restrict__ h,
    const float* __restrict__ w2, const float* __restrict__ b2,
    float* __restrict__ outf, short* __restrict__ outb)
{
  __shared__ float lG[64][4];
  int lc = blockIdx.x, b = blockIdx.y, t = threadIdx.x;
  int wid = t >> 6, lane = t & 63;
  int l0 = lc * 64;
  // gates: 8 positions per wave
  #pragma unroll
  for (int pi = 0; pi < 8; ++pi) {
    int pos = wid * 8 + pi;
    long row = (long)b * L_ + l0 + pos;
    short4v hh = *(const short4v*)(h + row * HID + lane * 4);
    float hv[4];
    #pragma unroll
    for (int j = 0; j < 4; ++j) hv[j] = b2f(hh[j]);
    float lg[3];
    #pragma unroll
    for (int e = 0; e < 3; ++e) {
      const float* wrow = w2 + e * HID + lane * 4;
      float p = hv[0] * wrow[0] + hv[1] * wrow[1] + hv[2] * wrow[2] + hv[3] * wrow[3];
      #pragma unroll
      for (int off = 32; off >= 1; off >>= 1) p += __shfl_xor(p, off);
      lg[e] = p + b2[e];
    }
    float mx = fmaxf(lg[0], fmaxf(lg[1], lg[2]));
    float e0 = __expf(lg[0] - mx), e1 = __expf(lg[1] - mx), e2 = __expf(lg[2] - mx);
    float inv = 1.f / (e0 + e1 + e2);
    float gv = (lane == 0) ? e0 * inv : (lane == 1) ? e1 * inv : e2 * inv;
    if (lane < 3) lG[pos][lane] = gv;
  }
  __syncthreads();

  int d = t;  // 512 threads = D
  const short* xb = xin + (long)b * L_ * D_ + d;
  float win[7];
  #pragma unroll
  for (int j = 0; j < 6; ++j) {
    int l = l0 - 3 + j;
    win[j] = (l >= 0 && l < L_) ? b2f(xb[(long)l * D_]) : 0.f;
  }
  for (int i = 0; i < 64; ++i) {
    int lcn = l0 + i;
    int lr = lcn + 3;
    win[6] = (lr < L_) ? b2f(xb[(long)lr * D_]) : 0.f;
    float s3 = win[2] + win[3] + win[4];
    float s5 = s3 + win[1] + win[5];
    float s7 = s5 + win[0] + win[6];
    float trend = lG[i][0] * s3 * (1.f / 3.f) + lG[i][1] * s5 * (1.f / 5.f)
                + lG[i][2] * s7 * (1.f / 7.f);
    float v = win[3] - trend;
    long o = ((long)b * L_ + lcn) * D_ + d;
    if (OUTF)   outf[o] = v;
    if (WRITEB) outb[o] = f2b(v);
    #pragma unroll
    for (int j = 0; j < 6; ++j) win[j] = win[j + 1];
  }
}

extern "C" void kernel_launch(void* const* d_in, const int* in_sizes, int n_in,
                              void* d_out, int out_size, void* d_ws, size_t ws_size,
                              hipStream_t stream) {
  const float* x       = (const float*)d_in[0];
  const float* w_real  = (const float*)d_in[1];
  const float* w_imag  = (const float*)d_in[2];
  const float* conv1_w = (const float*)d_in[3];
  const float* conv2_w = (const float*)d_in[4];
  const float* d1_w1   = (const float*)d_in[5];
  const float* d1_b1   = (const float*)d_in[6];
  const float* d1_w2   = (const float*)d_in[7];
  const float* d1_b2   = (const float*)d_in[8];
  const float* d2_w1   = (const float*)d_in[9];
  const float* d2_b1   = (const float*)d_in[10];
  const float* d2_w2   = (const float*)d_in[11];
  const float* d2_b2   = (const float*)d_in[12];
  float* OUT = (float*)d_out;

  // BIG (ws >= 144,703,488): full-M FFN (confirmed taken in R4: FETCH 127 MB).
  // SMALL (ws >= 98,566,144): 2-chunk FFN fallback.
  const size_t REQ_BIG = 144703488, REQ_SMALL = 98566144;
  if (ws_size < REQ_SMALL) {
    zero_out<<<(out_size + 255) / 256, 256, 0, stream>>>(OUT, out_size);
    return;
  }
  const bool big = (ws_size >= REQ_BIG);

  char* ws = (char*)d_ws;
  short* C1WB  = (short*)(ws + 0);          //  2,097,152
  short* C2WB  = (short*)(ws + 2097152);    //  2,097,152
  short* D1W1B = (short*)(ws + 4194304);    //    262,144
  short* D2W1B = (short*)(ws + 4456448);    //    262,144
  short* TCS   = (short*)(ws + 4718592);    //    393,216
  short* BASIS = (short*)(ws + 5111808);    //    393,216 (pad -> 6,291,456)
  short* XT    = (short*)(ws + 6291456);    // 25,165,824 [dead after fwdDFT]
  short* Y1    = XT;                        // big:100.7MB / small:50.3MB [FFN phase]
  short* QRI   = (short*)(ws + 31457280);   //  2,097,152 [written by fwdDFT col-store; dead after modes]
  short* OUTM  = (short*)(ws + 33554432);   //  2,097,152 [dead after invDFT]
  short* WTR   = (short*)(ws + 35651584);   // 33,554,432 [dead after modes]
  short* X1B   = WTR;                       // 25,165,824 [alias; dead after combine1]
  short* WTI   = (short*)(ws + 69206016);   // 33,554,432 [dead after modes]
  short* X2B   = (short*)(ws + (big ? 106954752 : 60817408));   // 25,165,824 (FFN2 in-place)
  short* H     = (short*)(ws + (big ? 132120576 : 85983232));   // 12,582,912

  // --- prep: all converts + DFT tables in ONE dispatch ---
  prep_all<<<3840, 256, 0, stream>>>(conv1_w, conv2_w, d1_w1, d2_w1,
                                     C1WB, C2WB, D1W1B, D2W1B, TCS, BASIS);
  transpose_w<<<dim3(8, 512, 8), 256, 0, stream>>>(w_real, w_imag, WTR, WTI);
  transpose_x<<<dim3(8, 24, 16), 256, 0, stream>>>(x, XT);

  // --- forward DFT with col-major store: QRI[c][bd] directly (csr=1, csc=8192) ---
  gemm64<false, false><<<dim3(128, 2), 256, 0, stream>>>(
      XT, L_, TCS, L_, nullptr, QRI, 1, (long)B_ * D_, L_);

  // --- per-mode complex matmul ---
  mode_gemm<<<dim3(64, 8), 256, 0, stream>>>(QRI, QRI + 64 * B_ * D_, WTR, WTI, OUTM);

  // --- inverse DFT + residual: x1 = x + irfft ---
  gemm128<false, false, true, false><<<dim3(12, 4, 16), 256, 0, stream>>>(
      BASIS, 128, 0, OUTM, 128, (long)D_ * 128, nullptr,
      x, D_, (long)L_ * D_, X1B, D_, (long)L_ * D_, 128);

  // --- decomp 1: H gemm, then fused gates+combine ---
  gemm64<true, true><<<dim3(384, 4), 256, 0, stream>>>(
      X1B, D_, D1W1B, D_, d1_b1, H, HID, 1, D_);
  combine_kernel<false, true><<<dim3(24, 16), 512, 0, stream>>>(
      X1B, H, d1_w2, d1_b2, nullptr, X2B);

  // --- FFN (big: single full-M pass; small: 2 row-chunks). FFN2 in-place into X2B. ---
  {
    const int nchunk = big ? 1 : 2;
    const long rows = big ? 24576 : 12288;
    for (int rc = 0; rc < nchunk; ++rc) {
      short* Ain = X2B + (long)rc * rows * D_;
      gemm128<true, false, false, false><<<dim3(rows / 128, 16, 1), 256, 0, stream>>>(
          Ain, D_, 0, C1WB, D_, 0, nullptr, nullptr, 0, 0, Y1, DFF_, 0, D_);
      gemm128<false, false, true, true><<<dim3(rows / 128, 4, 1), 256, 0, stream>>>(
          Y1, DFF_, 0, C2WB, DFF_, 0, nullptr, Ain, D_, 0, Ain, D_, 0, DFF_);
    }
  }

  // --- decomp 2 -> d_out ---
  gemm64<true, true><<<dim3(384, 4), 256, 0, stream>>>(
      X2B, D_, D2W1B, D_, d2_b1, H, HID, 1, D_);
  combine_kernel<true, false><<<dim3(24, 16), 512, 0, stream>>>(
      X2B, H, d2_w2, d2_b2, OUT, nullptr);
}